// Round 4
// baseline (343.555 us; speedup 1.0000x reference)
//
#include <hip/hip_runtime.h>
#include <hip/hip_fp16.h>

#define N_NODES 50000
#define N_EDGES 800000
#define D_IN 128
#define D_HID 256
#define D_OUT 128
#define NCHUNK 196   // ceil(N_NODES / 256)
#define NTILES 3125  // N_NODES / 16 exact

typedef _Float16 f16x8 __attribute__((ext_vector_type(8)));
typedef float f32x4 __attribute__((ext_vector_type(4)));

// ---------------- fused prep: zero_deg + cvt x + cvt weights ------------------
// 16B/lane vectorized: blocks [0,3125): xb; [3125,3141): 4 weight mats;
// [3141,3337): zero deg.

__device__ __forceinline__ void cvt8(const float* __restrict__ src,
                                     __half* __restrict__ dstp, int i) {
    const float4* s4 = (const float4*)src;
    float4 a = s4[i * 2];
    float4 b = s4[i * 2 + 1];
    float4 o;
    __half2* op = (__half2*)&o;
    op[0] = __float22half2_rn(make_float2(a.x, a.y));
    op[1] = __float22half2_rn(make_float2(a.z, a.w));
    op[2] = __float22half2_rn(make_float2(b.x, b.y));
    op[3] = __float22half2_rn(make_float2(b.z, b.w));
    ((float4*)dstp)[i] = o;
}

__global__ __launch_bounds__(256)
void prep_kernel(const float* __restrict__ x, __half* __restrict__ xb,
                 const float* __restrict__ Wl1, const float* __restrict__ Wr1,
                 const float* __restrict__ Wl2, const float* __restrict__ Wr2,
                 __half* __restrict__ wl1h, __half* __restrict__ wr1h,
                 __half* __restrict__ wl2h, __half* __restrict__ wr2h,
                 int* __restrict__ deg) {
    int b = blockIdx.x;
    if (b < 3125) {
        int i = b * 256 + threadIdx.x;            // 800000 threads x 8 floats
        cvt8(x, xb, i);
    } else if (b < 3141) {
        int i = (b - 3125) * 256 + threadIdx.x;   // 4096 threads x 8 floats/mat
        cvt8(Wl1, wl1h, i);
        cvt8(Wr1, wr1h, i);
        cvt8(Wl2, wl2h, i);
        cvt8(Wr2, wr2h, i);
    } else {
        int i = (b - 3141) * 256 + threadIdx.x;
        if (i < N_NODES) deg[i] = 0;
    }
}

// ---------------- CSR build: rank-split (atomic pass separated from scatter) --

__global__ void deg_rank_kernel(const int* __restrict__ dst, int* __restrict__ deg,
                                int* __restrict__ rank) {
    int i = blockIdx.x * blockDim.x + threadIdx.x;
    if (i < N_EDGES) rank[i] = atomicAdd(&deg[dst[i]], 1);
}

__global__ void chunk_sum(const int* __restrict__ deg, int* __restrict__ partial) {
    __shared__ int s[256];
    int i = blockIdx.x * 256 + threadIdx.x;
    s[threadIdx.x] = (i < N_NODES) ? deg[i] : 0;
    __syncthreads();
    for (int off = 128; off > 0; off >>= 1) {
        if (threadIdx.x < off) s[threadIdx.x] += s[threadIdx.x + off];
        __syncthreads();
    }
    if (threadIdx.x == 0) partial[blockIdx.x] = s[0];
}

// Per-chunk scan with integrated cross-chunk base.
__global__ void scatter_scan(const int* __restrict__ deg, const int* __restrict__ partial,
                             int* __restrict__ row_ptr, float* __restrict__ deg_inv) {
    __shared__ int s[256];
    __shared__ int base_s;
    const int tid = threadIdx.x;
    const int bid = blockIdx.x;
    s[tid] = (tid < bid) ? partial[tid] : 0;
    __syncthreads();
    for (int off = 128; off > 0; off >>= 1) {
        if (tid < off) s[tid] += s[tid + off];
        __syncthreads();
    }
    if (tid == 0) base_s = s[0];
    __syncthreads();
    int i = bid * 256 + tid;
    int v = (i < N_NODES) ? deg[i] : 0;
    s[tid] = v;
    __syncthreads();
    for (int off = 1; off < 256; off <<= 1) {
        int t = (tid >= off) ? s[tid - off] : 0;
        __syncthreads();
        s[tid] += t;
        __syncthreads();
    }
    if (i < N_NODES) {
        int rp = base_s + s[tid] - v;   // exclusive scan value
        row_ptr[i] = rp;
        deg_inv[i] = 1.0f / fmaxf((float)v, 1.0f);
        if (i == N_NODES - 1) row_ptr[N_NODES] = N_EDGES;
    }
}

// Atomic-free scatter: position = row_ptr[dst] + rank.
__global__ void fill_csr(const int* __restrict__ src, const int* __restrict__ dst,
                         const int* __restrict__ rank, const int* __restrict__ row_ptr,
                         int* __restrict__ csr_src) {
    int e = blockIdx.x * blockDim.x + threadIdx.x;
    if (e < N_EDGES) {
        csr_src[row_ptr[dst[e]] + rank[e]] = src[e];
    }
}

// ---------------- mean aggregation (full-TLP standalone kernels) -------------
// coalesced index preload (1 lane-parallel csr_src load per 64 edges,
// distributed via __shfl); packed float2 accumulation.

__device__ __forceinline__ void add_row(const float4& v, float2 (&acc)[4]) {
    const __half2* hp = (const __half2*)&v;
    #pragma unroll
    for (int j = 0; j < 4; ++j) {
        float2 f = __half22float2(hp[j]);
        acc[j].x += f.x;
        acc[j].y += f.y;
    }
}

template<bool ACCUM_F32>
__device__ __forceinline__ void gather_core(const __half2* __restrict__ feat,
                                            const int* __restrict__ row_ptr,
                                            const int* __restrict__ csr_src,
                                            const float* __restrict__ deg_inv,
                                            __half2* __restrict__ outh,
                                            float* __restrict__ outf) {
    const float4* feat4 = (const float4*)feat;
    const int lane = threadIdx.x & 63;
    const int g = lane >> 4;          // edge slot 0..3
    const int s = lane & 15;          // 16B chunk within row
    const int n = blockIdx.x * 4 + (threadIdx.x >> 6);
    const int beg = row_ptr[n];
    const int end = row_ptr[n + 1];
    float2 acc[4] = {};

    int idx = (beg + lane < end) ? csr_src[beg + lane] : 0;
    int base = beg;
    while (base < end) {
        int cnt = end - base;
        if (cnt > 64) cnt = 64;
        const int nbase = base + 64;
        int nidx = (nbase + lane < end) ? csr_src[nbase + lane] : 0;

        int it = 0;
        for (; it + 16 <= cnt; it += 16) {  // 4 independent 4-row loads in flight
            int s0 = __shfl(idx, it + g);
            int s1 = __shfl(idx, it + 4 + g);
            int s2 = __shfl(idx, it + 8 + g);
            int s3 = __shfl(idx, it + 12 + g);
            float4 v0 = feat4[(size_t)s0 * 16 + s];
            float4 v1 = feat4[(size_t)s1 * 16 + s];
            float4 v2 = feat4[(size_t)s2 * 16 + s];
            float4 v3 = feat4[(size_t)s3 * 16 + s];
            add_row(v0, acc);
            add_row(v1, acc);
            add_row(v2, acc);
            add_row(v3, acc);
        }
        for (; it + 4 <= cnt; it += 4) {
            int s0 = __shfl(idx, it + g);
            float4 v0 = feat4[(size_t)s0 * 16 + s];
            add_row(v0, acc);
        }
        if (it < cnt) {                   // masked tail (1..3 edges)
            int s0 = __shfl(idx, it + g);
            if (g < cnt - it) {
                float4 v0 = feat4[(size_t)s0 * 16 + s];
                add_row(v0, acc);
            }
        }
        idx = nidx;
        base = nbase;
    }

    #pragma unroll
    for (int j = 0; j < 4; ++j) {
        acc[j].x += __shfl_xor(acc[j].x, 16);
        acc[j].y += __shfl_xor(acc[j].y, 16);
        acc[j].x += __shfl_xor(acc[j].x, 32);
        acc[j].y += __shfl_xor(acc[j].y, 32);
    }
    if (g == 0) {
        float di = deg_inv[n];
        if (ACCUM_F32) {
            float4* orow = (float4*)(outf + (size_t)n * 128);
            float4 o0 = orow[s * 2];
            float4 o1 = orow[s * 2 + 1];
            o0.x += acc[0].x * di; o0.y += acc[0].y * di;
            o0.z += acc[1].x * di; o0.w += acc[1].y * di;
            o1.x += acc[2].x * di; o1.y += acc[2].y * di;
            o1.z += acc[3].x * di; o1.w += acc[3].y * di;
            orow[s * 2] = o0;
            orow[s * 2 + 1] = o1;
        } else {
            float4 o;
            __half2* op = (__half2*)&o;
            op[0] = __float22half2_rn(make_float2(acc[0].x * di, acc[0].y * di));
            op[1] = __float22half2_rn(make_float2(acc[1].x * di, acc[1].y * di));
            op[2] = __float22half2_rn(make_float2(acc[2].x * di, acc[2].y * di));
            op[3] = __float22half2_rn(make_float2(acc[3].x * di, acc[3].y * di));
            ((float4*)(outh + (size_t)n * 64))[s] = o;
        }
    }
}

__global__ __launch_bounds__(256)
void gather_mean_h(const __half2* __restrict__ feat, const int* __restrict__ row_ptr,
                   const int* __restrict__ csr_src, const float* __restrict__ deg_inv,
                   __half2* __restrict__ outv) {
    gather_core<false>(feat, row_ptr, csr_src, deg_inv, outv, nullptr);
}

__global__ __launch_bounds__(256)
void gather_mean_add_f32(const __half2* __restrict__ feat, const int* __restrict__ row_ptr,
                         const int* __restrict__ csr_src, const float* __restrict__ deg_inv,
                         float* __restrict__ out) {
    gather_core<true>(feat, row_ptr, csr_src, deg_inv, nullptr, out);
}

// ---------------- barrier-free MFMA GEMMs ------------------------------------
// No LDS, no __syncthreads: every wave owns an independent output tile.
// mfma_f32_16x16x32_f16 layouts (verified R4..R11 + round-2/3 numerics):
//   A frag: lane holds A[m = lane&15][k = kc*32 + (lane>>4)*8 + j]
//   B frag: lane holds W[n = lane&15][k]  (W row-major [J,K])
//   C/D:    col = lane&15 (n), row = (lane>>4)*4 + reg
// Task order: col-tile fastest -> adjacent waves/blocks share A rows (L2-hot);
// weights are tiny (192 KB total) and stay L1/L2-hot.

// L1: h[50000x256] = relu(mean1@Wl1^T + xb@Wr1^T + b1)
// task = 16-row x 32-col tile: 3125 x 8 = 25000 waves, 6250 blocks.
__global__ __launch_bounds__(256)
void gemm_l1(const __half* __restrict__ Aa,   // mean1 fp16 [N,128]
             const __half* __restrict__ Ab,   // xb fp16 [N,128]
             const __half* __restrict__ Wl1h, const __half* __restrict__ Wr1h,
             const float* __restrict__ bias1,
             __half* __restrict__ h) {
    const int lane = threadIdx.x & 63;
    const int task = blockIdx.x * 4 + (threadIdx.x >> 6);
    const int rt = task >> 3;              // row tile (16 rows)
    const int ct = task & 7;               // col tile (32 cols of 256)
    const int quad = lane >> 4;
    const int l16 = lane & 15;
    const int koff = quad * 8;

    f16x8 am[4], ax[4];
    const size_t arow = (size_t)(rt * 16 + l16) * D_IN + koff;
    #pragma unroll
    for (int kc = 0; kc < 4; ++kc) {
        am[kc] = *(const f16x8*)(Aa + arow + kc * 32);
        ax[kc] = *(const f16x8*)(Ab + arow + kc * 32);
    }
    f16x8 bl[4][2], br[4][2];
    #pragma unroll
    for (int kc = 0; kc < 4; ++kc)
        #pragma unroll
        for (int nt = 0; nt < 2; ++nt) {
            size_t brow = (size_t)(ct * 32 + nt * 16 + l16) * D_IN + kc * 32 + koff;
            bl[kc][nt] = *(const f16x8*)(Wl1h + brow);
            br[kc][nt] = *(const f16x8*)(Wr1h + brow);
        }
    f32x4 acc[2] = {};
    #pragma unroll
    for (int kc = 0; kc < 4; ++kc)
        #pragma unroll
        for (int nt = 0; nt < 2; ++nt) {
            acc[nt] = __builtin_amdgcn_mfma_f32_16x16x32_f16(
                am[kc], bl[kc][nt], acc[nt], 0, 0, 0);
            acc[nt] = __builtin_amdgcn_mfma_f32_16x16x32_f16(
                ax[kc], br[kc][nt], acc[nt], 0, 0, 0);
        }
    #pragma unroll
    for (int nt = 0; nt < 2; ++nt) {
        const int col = ct * 32 + nt * 16 + l16;
        const float bv = bias1[col];
        #pragma unroll
        for (int r = 0; r < 4; ++r) {
            int row = rt * 16 + quad * 4 + r;
            h[(size_t)row * D_HID + col] =
                __float2half(fmaxf(acc[nt][r] + bv, 0.f));
        }
    }
}

// L2: P[50000x128] = h@Wl2^T (fp16) ; OUT[50000x128] = h@Wr2^T + b2 (f32)
// task = 16-row x 16-col tile of both outputs: 3125 x 8 = 25000 waves.
__global__ __launch_bounds__(256)
void gemm_l2(const __half* __restrict__ h,
             const __half* __restrict__ B20, const __half* __restrict__ B21,
             const float* __restrict__ bias2,
             __half* __restrict__ P, float* __restrict__ out) {
    const int lane = threadIdx.x & 63;
    const int task = blockIdx.x * 4 + (threadIdx.x >> 6);
    const int rt = task >> 3;              // row tile (16 rows)
    const int ct = task & 7;               // col tile (16 cols of 128)
    const int quad = lane >> 4;
    const int l16 = lane & 15;
    const int koff = quad * 8;

    f16x8 ah[8];
    const size_t arow = (size_t)(rt * 16 + l16) * D_HID + koff;
    #pragma unroll
    for (int kc = 0; kc < 8; ++kc)
        ah[kc] = *(const f16x8*)(h + arow + kc * 32);
    f16x8 b0[8], b1[8];
    #pragma unroll
    for (int kc = 0; kc < 8; ++kc) {
        size_t brow = (size_t)(ct * 16 + l16) * D_HID + kc * 32 + koff;
        b0[kc] = *(const f16x8*)(B20 + brow);
        b1[kc] = *(const f16x8*)(B21 + brow);
    }
    f32x4 acc0 = {}, acc1 = {};
    #pragma unroll
    for (int kc = 0; kc < 8; ++kc) {
        acc0 = __builtin_amdgcn_mfma_f32_16x16x32_f16(ah[kc], b0[kc], acc0, 0, 0, 0);
        acc1 = __builtin_amdgcn_mfma_f32_16x16x32_f16(ah[kc], b1[kc], acc1, 0, 0, 0);
    }
    const int col = ct * 16 + l16;
    const float bv = bias2[col];
    #pragma unroll
    for (int r = 0; r < 4; ++r) {
        int row = rt * 16 + quad * 4 + r;
        P[(size_t)row * D_OUT + col] = __float2half(acc0[r]);
        out[(size_t)row * D_OUT + col] = acc1[r] + bv;
    }
}

extern "C" void kernel_launch(void* const* d_in, const int* in_sizes, int n_in,
                              void* d_out, int out_size, void* d_ws, size_t ws_size,
                              hipStream_t stream) {
    const float* x   = (const float*)d_in[0];
    const float* Wl1 = (const float*)d_in[1];
    const float* bl1 = (const float*)d_in[2];
    const float* Wr1 = (const float*)d_in[3];
    const float* Wl2 = (const float*)d_in[4];
    const float* bl2 = (const float*)d_in[5];
    const float* Wr2 = (const float*)d_in[6];
    const int*   ei  = (const int*)d_in[7];
    const int* src = ei;              // edge_index[0]
    const int* dst = ei + N_EDGES;    // edge_index[1]
    float* out = (float*)d_out;

    // Workspace layout, 256B-aligned slabs
    char* w = (char*)d_ws;
    auto alloc = [&](size_t bytes) {
        char* r = w;
        w += (bytes + 255) & ~(size_t)255;
        return r;
    };
    int*     deg       = (int*)alloc((size_t)N_NODES * 4);
    int*     row_ptr   = (int*)alloc((size_t)(N_NODES + 1) * 4);
    int*     rank      = (int*)alloc((size_t)N_EDGES * 4);
    int*     partial   = (int*)alloc(NCHUNK * 4);
    int*     csr_src   = (int*)alloc((size_t)N_EDGES * 4);
    float*   deg_inv   = (float*)alloc((size_t)N_NODES * 4);
    __half2* xb        = (__half2*)alloc((size_t)N_NODES * 64 * 4);   // x fp16
    __half2* mean1     = (__half2*)alloc((size_t)N_NODES * 64 * 4);   // mean(x) fp16
    __half*  hbuf      = (__half*)alloc((size_t)N_NODES * D_HID * 2); // h fp16
    __half2* pb        = (__half2*)alloc((size_t)N_NODES * 64 * 4);   // h@Wl2^T fp16
    __half*  wl1h      = (__half*)alloc(4 * 32768 * 2);
    __half*  wr1h = wl1h + 32768;
    __half*  wl2h = wr1h + 32768;
    __half*  wr2h = wl2h + 32768;

    // Fused prep: x->fp16, weights->fp16, deg=0 (one dispatch)
    prep_kernel<<<3337, 256, 0, stream>>>(x, (__half*)xb, Wl1, Wr1, Wl2, Wr2,
        wl1h, wr1h, wl2h, wr2h, deg);

    // CSR build
    deg_rank_kernel<<<(N_EDGES + 255) / 256, 256, 0, stream>>>(dst, deg, rank);
    chunk_sum<<<NCHUNK, 256, 0, stream>>>(deg, partial);
    scatter_scan<<<NCHUNK, 256, 0, stream>>>(deg, partial, row_ptr, deg_inv);
    fill_csr<<<(N_EDGES + 255) / 256, 256, 0, stream>>>(src, dst, rank, row_ptr, csr_src);

    // Layer 1 aggregation (full TLP: 12500 blocks, wave per node)
    gather_mean_h<<<12500, 256, 0, stream>>>(xb, row_ptr, csr_src, deg_inv, mean1);

    // Barrier-free GEMMs: h = relu(mean1@Wl1^T + xb@Wr1^T + b1)
    gemm_l1<<<6250, 256, 0, stream>>>(
        (const __half*)mean1, (const __half*)xb, wl1h, wr1h, bl1, hbuf);

    // P = h@Wl2^T ; out = h@Wr2^T + b2
    gemm_l2<<<6250, 256, 0, stream>>>(hbuf, wl2h, wr2h, bl2, (__half*)pb, out);

    // out += mean(P)
    gather_mean_add_f32<<<12500, 256, 0, stream>>>(pb, row_ptr, csr_src, deg_inv, out);
}

// Round 5
// 268.728 us; speedup vs baseline: 1.2784x; 1.2784x over previous
//
#include <hip/hip_runtime.h>
#include <hip/hip_fp16.h>

#define N_NODES 50000
#define N_EDGES 800000
#define D_IN 128
#define D_HID 256
#define D_OUT 128
#define NCHUNK 196   // ceil(N_NODES / 256)
#define NTILES 3125  // N_NODES / 16 exact

typedef _Float16 f16x8 __attribute__((ext_vector_type(8)));
typedef float f32x4 __attribute__((ext_vector_type(4)));

// ---------------- fused prep: zero_deg + cvt x + cvt weights ------------------
// 16B/lane vectorized: blocks [0,3125): xb; [3125,3141): 4 weight mats;
// [3141,3337): zero deg.

__device__ __forceinline__ void cvt8(const float* __restrict__ src,
                                     __half* __restrict__ dstp, int i) {
    const float4* s4 = (const float4*)src;
    float4 a = s4[i * 2];
    float4 b = s4[i * 2 + 1];
    float4 o;
    __half2* op = (__half2*)&o;
    op[0] = __float22half2_rn(make_float2(a.x, a.y));
    op[1] = __float22half2_rn(make_float2(a.z, a.w));
    op[2] = __float22half2_rn(make_float2(b.x, b.y));
    op[3] = __float22half2_rn(make_float2(b.z, b.w));
    ((float4*)dstp)[i] = o;
}

__global__ __launch_bounds__(256)
void prep_kernel(const float* __restrict__ x, __half* __restrict__ xb,
                 const float* __restrict__ Wl1, const float* __restrict__ Wr1,
                 const float* __restrict__ Wl2, const float* __restrict__ Wr2,
                 __half* __restrict__ wl1h, __half* __restrict__ wr1h,
                 __half* __restrict__ wl2h, __half* __restrict__ wr2h,
                 int* __restrict__ deg) {
    int b = blockIdx.x;
    if (b < 3125) {
        int i = b * 256 + threadIdx.x;            // 800000 threads x 8 floats
        cvt8(x, xb, i);
    } else if (b < 3141) {
        int i = (b - 3125) * 256 + threadIdx.x;   // 4096 threads x 8 floats/mat
        cvt8(Wl1, wl1h, i);
        cvt8(Wr1, wr1h, i);
        cvt8(Wl2, wl2h, i);
        cvt8(Wr2, wr2h, i);
    } else {
        int i = (b - 3141) * 256 + threadIdx.x;
        if (i < N_NODES) deg[i] = 0;
    }
}

// ---------------- CSR build: rank-split (atomic pass separated from scatter) --

__global__ void deg_rank_kernel(const int* __restrict__ dst, int* __restrict__ deg,
                                int* __restrict__ rank) {
    int i = blockIdx.x * blockDim.x + threadIdx.x;
    if (i < N_EDGES) rank[i] = atomicAdd(&deg[dst[i]], 1);
}

__global__ void chunk_sum(const int* __restrict__ deg, int* __restrict__ partial) {
    __shared__ int s[256];
    int i = blockIdx.x * 256 + threadIdx.x;
    s[threadIdx.x] = (i < N_NODES) ? deg[i] : 0;
    __syncthreads();
    for (int off = 128; off > 0; off >>= 1) {
        if (threadIdx.x < off) s[threadIdx.x] += s[threadIdx.x + off];
        __syncthreads();
    }
    if (threadIdx.x == 0) partial[blockIdx.x] = s[0];
}

// Per-chunk scan with integrated cross-chunk base.
__global__ void scatter_scan(const int* __restrict__ deg, const int* __restrict__ partial,
                             int* __restrict__ row_ptr, float* __restrict__ deg_inv) {
    __shared__ int s[256];
    __shared__ int base_s;
    const int tid = threadIdx.x;
    const int bid = blockIdx.x;
    s[tid] = (tid < bid) ? partial[tid] : 0;
    __syncthreads();
    for (int off = 128; off > 0; off >>= 1) {
        if (tid < off) s[tid] += s[tid + off];
        __syncthreads();
    }
    if (tid == 0) base_s = s[0];
    __syncthreads();
    int i = bid * 256 + tid;
    int v = (i < N_NODES) ? deg[i] : 0;
    s[tid] = v;
    __syncthreads();
    for (int off = 1; off < 256; off <<= 1) {
        int t = (tid >= off) ? s[tid - off] : 0;
        __syncthreads();
        s[tid] += t;
        __syncthreads();
    }
    if (i < N_NODES) {
        int rp = base_s + s[tid] - v;   // exclusive scan value
        row_ptr[i] = rp;
        deg_inv[i] = 1.0f / fmaxf((float)v, 1.0f);
        if (i == N_NODES - 1) row_ptr[N_NODES] = N_EDGES;
    }
}

// Atomic-free scatter: position = row_ptr[dst] + rank.
__global__ void fill_csr(const int* __restrict__ src, const int* __restrict__ dst,
                         const int* __restrict__ rank, const int* __restrict__ row_ptr,
                         int* __restrict__ csr_src) {
    int e = blockIdx.x * blockDim.x + threadIdx.x;
    if (e < N_EDGES) {
        csr_src[row_ptr[dst[e]] + rank[e]] = src[e];
    }
}

// ---------------- mean aggregation (full-TLP standalone kernels) -------------
// coalesced index preload (1 lane-parallel csr_src load per 64 edges,
// distributed via __shfl); packed float2 accumulation.

__device__ __forceinline__ void add_row(const float4& v, float2 (&acc)[4]) {
    const __half2* hp = (const __half2*)&v;
    #pragma unroll
    for (int j = 0; j < 4; ++j) {
        float2 f = __half22float2(hp[j]);
        acc[j].x += f.x;
        acc[j].y += f.y;
    }
}

template<bool ACCUM_F32>
__device__ __forceinline__ void gather_core(const __half2* __restrict__ feat,
                                            const int* __restrict__ row_ptr,
                                            const int* __restrict__ csr_src,
                                            const float* __restrict__ deg_inv,
                                            __half2* __restrict__ outh,
                                            float* __restrict__ outf) {
    const float4* feat4 = (const float4*)feat;
    const int lane = threadIdx.x & 63;
    const int g = lane >> 4;          // edge slot 0..3
    const int s = lane & 15;          // 16B chunk within row
    const int n = blockIdx.x * 4 + (threadIdx.x >> 6);
    const int beg = row_ptr[n];
    const int end = row_ptr[n + 1];
    float2 acc[4] = {};

    int idx = (beg + lane < end) ? csr_src[beg + lane] : 0;
    int base = beg;
    while (base < end) {
        int cnt = end - base;
        if (cnt > 64) cnt = 64;
        const int nbase = base + 64;
        int nidx = (nbase + lane < end) ? csr_src[nbase + lane] : 0;

        int it = 0;
        for (; it + 16 <= cnt; it += 16) {  // 4 independent 4-row loads in flight
            int s0 = __shfl(idx, it + g);
            int s1 = __shfl(idx, it + 4 + g);
            int s2 = __shfl(idx, it + 8 + g);
            int s3 = __shfl(idx, it + 12 + g);
            float4 v0 = feat4[(size_t)s0 * 16 + s];
            float4 v1 = feat4[(size_t)s1 * 16 + s];
            float4 v2 = feat4[(size_t)s2 * 16 + s];
            float4 v3 = feat4[(size_t)s3 * 16 + s];
            add_row(v0, acc);
            add_row(v1, acc);
            add_row(v2, acc);
            add_row(v3, acc);
        }
        for (; it + 4 <= cnt; it += 4) {
            int s0 = __shfl(idx, it + g);
            float4 v0 = feat4[(size_t)s0 * 16 + s];
            add_row(v0, acc);
        }
        if (it < cnt) {                   // masked tail (1..3 edges)
            int s0 = __shfl(idx, it + g);
            if (g < cnt - it) {
                float4 v0 = feat4[(size_t)s0 * 16 + s];
                add_row(v0, acc);
            }
        }
        idx = nidx;
        base = nbase;
    }

    #pragma unroll
    for (int j = 0; j < 4; ++j) {
        acc[j].x += __shfl_xor(acc[j].x, 16);
        acc[j].y += __shfl_xor(acc[j].y, 16);
        acc[j].x += __shfl_xor(acc[j].x, 32);
        acc[j].y += __shfl_xor(acc[j].y, 32);
    }
    if (g == 0) {
        float di = deg_inv[n];
        if (ACCUM_F32) {
            float4* orow = (float4*)(outf + (size_t)n * 128);
            float4 o0 = orow[s * 2];
            float4 o1 = orow[s * 2 + 1];
            o0.x += acc[0].x * di; o0.y += acc[0].y * di;
            o0.z += acc[1].x * di; o0.w += acc[1].y * di;
            o1.x += acc[2].x * di; o1.y += acc[2].y * di;
            o1.z += acc[3].x * di; o1.w += acc[3].y * di;
            orow[s * 2] = o0;
            orow[s * 2 + 1] = o1;
        } else {
            float4 o;
            __half2* op = (__half2*)&o;
            op[0] = __float22half2_rn(make_float2(acc[0].x * di, acc[0].y * di));
            op[1] = __float22half2_rn(make_float2(acc[1].x * di, acc[1].y * di));
            op[2] = __float22half2_rn(make_float2(acc[2].x * di, acc[2].y * di));
            op[3] = __float22half2_rn(make_float2(acc[3].x * di, acc[3].y * di));
            ((float4*)(outh + (size_t)n * 64))[s] = o;
        }
    }
}

__global__ __launch_bounds__(256)
void gather_mean_h(const __half2* __restrict__ feat, const int* __restrict__ row_ptr,
                   const int* __restrict__ csr_src, const float* __restrict__ deg_inv,
                   __half2* __restrict__ outv) {
    gather_core<false>(feat, row_ptr, csr_src, deg_inv, outv, nullptr);
}

__global__ __launch_bounds__(256)
void gather_mean_add_f32(const __half2* __restrict__ feat, const int* __restrict__ row_ptr,
                         const int* __restrict__ csr_src, const float* __restrict__ deg_inv,
                         float* __restrict__ out) {
    gather_core<true>(feat, row_ptr, csr_src, deg_inv, nullptr, out);
}

// ---------------- barrier-free, B-amortized MFMA GEMMs -----------------------
// Quadrant analysis (R1/R3/R4): need BOTH per-wave B kept in regs across many
// row-tiles (amortization) AND zero __syncthreads (no vmcnt(0) drains).
// 256-thread blocks, wave owns a fixed col-slice; block parity picks the slice
// half; grid-stride over row tiles with double-buffered A-frag loads (proven
// loop shape from R1). No LDS.
// mfma_f32_16x16x32_f16 layouts (verified R4..R11 + rounds 2-4 numerics):
//   A frag: lane holds A[m = lane&15][k = kc*32 + (lane>>4)*8 + j]
//   B frag: lane holds W[n = lane&15][k]  (W row-major [J,K])
//   C/D:    col = lane&15 (n), row = (lane>>4)*4 + reg

// L1: h[50000x256] = relu(mean1@Wl1^T + xb@Wr1^T + b1)
// wave col-slice = 32 cols: ct = (blockIdx&1)*4 + wave.
__global__ __launch_bounds__(256, 2)
void gemm_l1(const __half* __restrict__ Aa,   // mean1 fp16 [N,128]
             const __half* __restrict__ Ab,   // xb fp16 [N,128]
             const __half* __restrict__ Wl1h, const __half* __restrict__ Wr1h,
             const float* __restrict__ bias1,
             __half* __restrict__ h) {
    const int lane = threadIdx.x & 63;
    const int wave = threadIdx.x >> 6;              // 0..3
    const int ct = ((blockIdx.x & 1) << 2) + wave;  // 0..7 (32 cols each)
    const int quad = lane >> 4;
    const int l16 = lane & 15;
    const int koff = quad * 8;

    // B-frags once per wave: 16 x f16x8 = 64 VGPR
    f16x8 bl[4][2], br[4][2];
    #pragma unroll
    for (int kc = 0; kc < 4; ++kc)
        #pragma unroll
        for (int nt = 0; nt < 2; ++nt) {
            size_t brow = (size_t)(ct * 32 + nt * 16 + l16) * D_IN + kc * 32 + koff;
            bl[kc][nt] = *(const f16x8*)(Wl1h + brow);
            br[kc][nt] = *(const f16x8*)(Wr1h + brow);
        }
    float bv[2];
    #pragma unroll
    for (int nt = 0; nt < 2; ++nt) bv[nt] = bias1[ct * 32 + nt * 16 + l16];

    const int g = gridDim.x >> 1;        // row-tile stride (pairs of blocks)

    auto loadA = [&](int t, f16x8 (&am)[4], f16x8 (&ax)[4]) {
        const size_t arow = (size_t)(t * 16 + l16) * D_IN + koff;
        #pragma unroll
        for (int kc = 0; kc < 4; ++kc) {
            am[kc] = *(const f16x8*)(Aa + arow + kc * 32);
            ax[kc] = *(const f16x8*)(Ab + arow + kc * 32);
        }
    };

    auto step = [&](int t, const f16x8 (&am)[4], const f16x8 (&ax)[4]) {
        f32x4 acc[2] = {};
        #pragma unroll
        for (int kc = 0; kc < 4; ++kc)
            #pragma unroll
            for (int nt = 0; nt < 2; ++nt) {
                acc[nt] = __builtin_amdgcn_mfma_f32_16x16x32_f16(
                    am[kc], bl[kc][nt], acc[nt], 0, 0, 0);
                acc[nt] = __builtin_amdgcn_mfma_f32_16x16x32_f16(
                    ax[kc], br[kc][nt], acc[nt], 0, 0, 0);
            }
        #pragma unroll
        for (int nt = 0; nt < 2; ++nt) {
            const int col = ct * 32 + nt * 16 + l16;
            #pragma unroll
            for (int r = 0; r < 4; ++r) {
                int row = t * 16 + quad * 4 + r;
                h[(size_t)row * D_HID + col] =
                    __float2half(fmaxf(acc[nt][r] + bv[nt], 0.f));
            }
        }
    };

    f16x8 am0[4], ax0[4], am1[4], ax1[4];
    int tile = blockIdx.x >> 1;
    if (tile >= NTILES) return;
    loadA(tile, am0, ax0);
    while (true) {
        if (tile + g < NTILES) loadA(tile + g, am1, ax1);
        step(tile, am0, ax0);
        tile += g;
        if (tile >= NTILES) break;
        if (tile + g < NTILES) loadA(tile + g, am0, ax0);
        step(tile, am1, ax1);
        tile += g;
        if (tile >= NTILES) break;
    }
}

// L2: P[50000x128] = h@Wl2^T (fp16) ; OUT[50000x128] = h@Wr2^T + b2 (f32)
// wave col-slice = 16 cols of each output: ct = (blockIdx&1)*4 + wave.
__global__ __launch_bounds__(256, 2)
void gemm_l2(const __half* __restrict__ h,
             const __half* __restrict__ B20, const __half* __restrict__ B21,
             const float* __restrict__ bias2,
             __half* __restrict__ P, float* __restrict__ out) {
    const int lane = threadIdx.x & 63;
    const int wave = threadIdx.x >> 6;
    const int ct = ((blockIdx.x & 1) << 2) + wave;  // 0..7 (16 cols each)
    const int quad = lane >> 4;
    const int l16 = lane & 15;
    const int koff = quad * 8;

    // B-frags once per wave: 16 x f16x8 = 64 VGPR
    f16x8 b0[8], b1[8];
    #pragma unroll
    for (int kc = 0; kc < 8; ++kc) {
        size_t brow = (size_t)(ct * 16 + l16) * D_HID + kc * 32 + koff;
        b0[kc] = *(const f16x8*)(B20 + brow);
        b1[kc] = *(const f16x8*)(B21 + brow);
    }
    const float bv = bias2[ct * 16 + l16];

    const int g = gridDim.x >> 1;

    auto loadA = [&](int t, f16x8 (&ah)[8]) {
        const size_t arow = (size_t)(t * 16 + l16) * D_HID + koff;
        #pragma unroll
        for (int kc = 0; kc < 8; ++kc)
            ah[kc] = *(const f16x8*)(h + arow + kc * 32);
    };

    auto step = [&](int t, const f16x8 (&ah)[8]) {
        f32x4 acc0 = {}, acc1 = {};
        #pragma unroll
        for (int kc = 0; kc < 8; ++kc) {
            acc0 = __builtin_amdgcn_mfma_f32_16x16x32_f16(ah[kc], b0[kc], acc0, 0, 0, 0);
            acc1 = __builtin_amdgcn_mfma_f32_16x16x32_f16(ah[kc], b1[kc], acc1, 0, 0, 0);
        }
        const int col = ct * 16 + l16;
        #pragma unroll
        for (int r = 0; r < 4; ++r) {
            int row = t * 16 + quad * 4 + r;
            P[(size_t)row * D_OUT + col] = __float2half(acc0[r]);
            out[(size_t)row * D_OUT + col] = acc1[r] + bv;
        }
    };

    f16x8 a0[8], a1[8];
    int tile = blockIdx.x >> 1;
    if (tile >= NTILES) return;
    loadA(tile, a0);
    while (true) {
        if (tile + g < NTILES) loadA(tile + g, a1);
        step(tile, a0);
        tile += g;
        if (tile >= NTILES) break;
        if (tile + g < NTILES) loadA(tile + g, a0);
        step(tile, a1);
        tile += g;
        if (tile >= NTILES) break;
    }
}

extern "C" void kernel_launch(void* const* d_in, const int* in_sizes, int n_in,
                              void* d_out, int out_size, void* d_ws, size_t ws_size,
                              hipStream_t stream) {
    const float* x   = (const float*)d_in[0];
    const float* Wl1 = (const float*)d_in[1];
    const float* bl1 = (const float*)d_in[2];
    const float* Wr1 = (const float*)d_in[3];
    const float* Wl2 = (const float*)d_in[4];
    const float* bl2 = (const float*)d_in[5];
    const float* Wr2 = (const float*)d_in[6];
    const int*   ei  = (const int*)d_in[7];
    const int* src = ei;              // edge_index[0]
    const int* dst = ei + N_EDGES;    // edge_index[1]
    float* out = (float*)d_out;

    // Workspace layout, 256B-aligned slabs
    char* w = (char*)d_ws;
    auto alloc = [&](size_t bytes) {
        char* r = w;
        w += (bytes + 255) & ~(size_t)255;
        return r;
    };
    int*     deg       = (int*)alloc((size_t)N_NODES * 4);
    int*     row_ptr   = (int*)alloc((size_t)(N_NODES + 1) * 4);
    int*     rank      = (int*)alloc((size_t)N_EDGES * 4);
    int*     partial   = (int*)alloc(NCHUNK * 4);
    int*     csr_src   = (int*)alloc((size_t)N_EDGES * 4);
    float*   deg_inv   = (float*)alloc((size_t)N_NODES * 4);
    __half2* xb        = (__half2*)alloc((size_t)N_NODES * 64 * 4);   // x fp16
    __half2* mean1     = (__half2*)alloc((size_t)N_NODES * 64 * 4);   // mean(x) fp16
    __half*  hbuf      = (__half*)alloc((size_t)N_NODES * D_HID * 2); // h fp16
    __half2* pb        = (__half2*)alloc((size_t)N_NODES * 64 * 4);   // h@Wl2^T fp16
    __half*  wl1h      = (__half*)alloc(4 * 32768 * 2);
    __half*  wr1h = wl1h + 32768;
    __half*  wl2h = wr1h + 32768;
    __half*  wr2h = wl2h + 32768;

    // Fused prep: x->fp16, weights->fp16, deg=0 (one dispatch)
    prep_kernel<<<3337, 256, 0, stream>>>(x, (__half*)xb, Wl1, Wr1, Wl2, Wr2,
        wl1h, wr1h, wl2h, wr2h, deg);

    // CSR build
    deg_rank_kernel<<<(N_EDGES + 255) / 256, 256, 0, stream>>>(dst, deg, rank);
    chunk_sum<<<NCHUNK, 256, 0, stream>>>(deg, partial);
    scatter_scan<<<NCHUNK, 256, 0, stream>>>(deg, partial, row_ptr, deg_inv);
    fill_csr<<<(N_EDGES + 255) / 256, 256, 0, stream>>>(src, dst, rank, row_ptr, csr_src);

    // Layer 1 aggregation (full TLP: 12500 blocks, wave per node)
    gather_mean_h<<<12500, 256, 0, stream>>>(xb, row_ptr, csr_src, deg_inv, mean1);

    // Barrier-free amortized GEMMs
    gemm_l1<<<1024, 256, 0, stream>>>(
        (const __half*)mean1, (const __half*)xb, wl1h, wr1h, bl1, hbuf);
    gemm_l2<<<1024, 256, 0, stream>>>(hbuf, wl2h, wr2h, bl2, (__half*)pb, out);

    // out += mean(P)
    gather_mean_add_f32<<<12500, 256, 0, stream>>>(pb, row_ptr, csr_src, deg_inv, out);
}

// Round 6
// 253.146 us; speedup vs baseline: 1.3571x; 1.0616x over previous
//
#include <hip/hip_runtime.h>
#include <hip/hip_fp16.h>

#define N_NODES 50000
#define N_EDGES 800000
#define D_IN 128
#define D_HID 256
#define D_OUT 128
#define NCHUNK 196   // ceil(N_NODES / 256)
#define NTILES 3125  // N_NODES / 16 exact
#define GEMM_GRID 256

typedef _Float16 f16x8 __attribute__((ext_vector_type(8)));
typedef float f32x4 __attribute__((ext_vector_type(4)));

// ---------------- merged prep + deg/rank --------------------------------------
// blocks [0,3125): x cvt; [3125,3141): 4 weight mats; [3141,6266): deg_rank.
// deg is zeroed by hipMemsetAsync before this dispatch.

__device__ __forceinline__ void cvt8(const float* __restrict__ src,
                                     __half* __restrict__ dstp, int i) {
    const float4* s4 = (const float4*)src;
    float4 a = s4[i * 2];
    float4 b = s4[i * 2 + 1];
    float4 o;
    __half2* op = (__half2*)&o;
    op[0] = __float22half2_rn(make_float2(a.x, a.y));
    op[1] = __float22half2_rn(make_float2(a.z, a.w));
    op[2] = __float22half2_rn(make_float2(b.x, b.y));
    op[3] = __float22half2_rn(make_float2(b.z, b.w));
    ((float4*)dstp)[i] = o;
}

__global__ __launch_bounds__(256)
void prep_deg_rank(const float* __restrict__ x, __half* __restrict__ xb,
                   const float* __restrict__ Wl1, const float* __restrict__ Wr1,
                   const float* __restrict__ Wl2, const float* __restrict__ Wr2,
                   __half* __restrict__ wl1h, __half* __restrict__ wr1h,
                   __half* __restrict__ wl2h, __half* __restrict__ wr2h,
                   const int* __restrict__ dst, int* __restrict__ deg,
                   int* __restrict__ rank) {
    int b = blockIdx.x;
    if (b < 3125) {
        int i = b * 256 + threadIdx.x;            // 800000 threads x 8 floats
        cvt8(x, xb, i);
    } else if (b < 3141) {
        int i = (b - 3125) * 256 + threadIdx.x;   // 4096 threads x 8 floats/mat
        cvt8(Wl1, wl1h, i);
        cvt8(Wr1, wr1h, i);
        cvt8(Wl2, wl2h, i);
        cvt8(Wr2, wr2h, i);
    } else {
        int e = (b - 3141) * 256 + threadIdx.x;   // 3125*256 = 800000 exact
        rank[e] = atomicAdd(&deg[dst[e]], 1);
    }
}

// ---------------- CSR scan (chunk_sum folded in) ------------------------------
// Each block directly sums deg[0 .. bid*256) for its base (coalesced, ~19MB of
// L2 reads total across 196 blocks), then per-chunk Hillis-Steele scan.

__global__ void scatter_scan(const int* __restrict__ deg,
                             int* __restrict__ row_ptr, float* __restrict__ deg_inv) {
    __shared__ int s[256];
    __shared__ int base_s;
    const int tid = threadIdx.x;
    const int bid = blockIdx.x;
    // base = sum deg[0 .. bid*256)
    int sum = 0;
    for (int j = tid; j < bid * 256; j += 256) sum += deg[j];
    s[tid] = sum;
    __syncthreads();
    for (int off = 128; off > 0; off >>= 1) {
        if (tid < off) s[tid] += s[tid + off];
        __syncthreads();
    }
    if (tid == 0) base_s = s[0];
    __syncthreads();
    // per-chunk inclusive scan
    int i = bid * 256 + tid;
    int v = (i < N_NODES) ? deg[i] : 0;
    s[tid] = v;
    __syncthreads();
    for (int off = 1; off < 256; off <<= 1) {
        int t = (tid >= off) ? s[tid - off] : 0;
        __syncthreads();
        s[tid] += t;
        __syncthreads();
    }
    if (i < N_NODES) {
        int rp = base_s + s[tid] - v;   // exclusive scan value
        row_ptr[i] = rp;
        deg_inv[i] = 1.0f / fmaxf((float)v, 1.0f);
        if (i == N_NODES - 1) row_ptr[N_NODES] = N_EDGES;
    }
}

// Atomic-free scatter: position = row_ptr[dst] + rank.
__global__ void fill_csr(const int* __restrict__ src, const int* __restrict__ dst,
                         const int* __restrict__ rank, const int* __restrict__ row_ptr,
                         int* __restrict__ csr_src) {
    int e = blockIdx.x * blockDim.x + threadIdx.x;
    if (e < N_EDGES) {
        csr_src[row_ptr[dst[e]] + rank[e]] = src[e];
    }
}

// ---------------- mean aggregation (full-TLP standalone kernels) -------------
// coalesced index preload (1 lane-parallel csr_src load per 64 edges,
// distributed via __shfl); packed float2 accumulation.

__device__ __forceinline__ void add_row(const float4& v, float2 (&acc)[4]) {
    const __half2* hp = (const __half2*)&v;
    #pragma unroll
    for (int j = 0; j < 4; ++j) {
        float2 f = __half22float2(hp[j]);
        acc[j].x += f.x;
        acc[j].y += f.y;
    }
}

template<bool ACCUM_F32>
__device__ __forceinline__ void gather_core(const __half2* __restrict__ feat,
                                            const int* __restrict__ row_ptr,
                                            const int* __restrict__ csr_src,
                                            const float* __restrict__ deg_inv,
                                            __half2* __restrict__ outh,
                                            float* __restrict__ outf) {
    const float4* feat4 = (const float4*)feat;
    const int lane = threadIdx.x & 63;
    const int g = lane >> 4;          // edge slot 0..3
    const int s = lane & 15;          // 16B chunk within row
    const int n = blockIdx.x * 4 + (threadIdx.x >> 6);
    const int beg = row_ptr[n];
    const int end = row_ptr[n + 1];
    float2 acc[4] = {};

    int idx = (beg + lane < end) ? csr_src[beg + lane] : 0;
    int base = beg;
    while (base < end) {
        int cnt = end - base;
        if (cnt > 64) cnt = 64;
        const int nbase = base + 64;
        int nidx = (nbase + lane < end) ? csr_src[nbase + lane] : 0;

        int it = 0;
        for (; it + 16 <= cnt; it += 16) {  // 4 independent 4-row loads in flight
            int s0 = __shfl(idx, it + g);
            int s1 = __shfl(idx, it + 4 + g);
            int s2 = __shfl(idx, it + 8 + g);
            int s3 = __shfl(idx, it + 12 + g);
            float4 v0 = feat4[(size_t)s0 * 16 + s];
            float4 v1 = feat4[(size_t)s1 * 16 + s];
            float4 v2 = feat4[(size_t)s2 * 16 + s];
            float4 v3 = feat4[(size_t)s3 * 16 + s];
            add_row(v0, acc);
            add_row(v1, acc);
            add_row(v2, acc);
            add_row(v3, acc);
        }
        for (; it + 4 <= cnt; it += 4) {
            int s0 = __shfl(idx, it + g);
            float4 v0 = feat4[(size_t)s0 * 16 + s];
            add_row(v0, acc);
        }
        if (it < cnt) {                   // masked tail (1..3 edges)
            int s0 = __shfl(idx, it + g);
            if (g < cnt - it) {
                float4 v0 = feat4[(size_t)s0 * 16 + s];
                add_row(v0, acc);
            }
        }
        idx = nidx;
        base = nbase;
    }

    #pragma unroll
    for (int j = 0; j < 4; ++j) {
        acc[j].x += __shfl_xor(acc[j].x, 16);
        acc[j].y += __shfl_xor(acc[j].y, 16);
        acc[j].x += __shfl_xor(acc[j].x, 32);
        acc[j].y += __shfl_xor(acc[j].y, 32);
    }
    if (g == 0) {
        float di = deg_inv[n];
        if (ACCUM_F32) {
            float4* orow = (float4*)(outf + (size_t)n * 128);
            float4 o0 = orow[s * 2];
            float4 o1 = orow[s * 2 + 1];
            o0.x += acc[0].x * di; o0.y += acc[0].y * di;
            o0.z += acc[1].x * di; o0.w += acc[1].y * di;
            o1.x += acc[2].x * di; o1.y += acc[2].y * di;
            o1.z += acc[3].x * di; o1.w += acc[3].y * di;
            orow[s * 2] = o0;
            orow[s * 2 + 1] = o1;
        } else {
            float4 o;
            __half2* op = (__half2*)&o;
            op[0] = __float22half2_rn(make_float2(acc[0].x * di, acc[0].y * di));
            op[1] = __float22half2_rn(make_float2(acc[1].x * di, acc[1].y * di));
            op[2] = __float22half2_rn(make_float2(acc[2].x * di, acc[2].y * di));
            op[3] = __float22half2_rn(make_float2(acc[3].x * di, acc[3].y * di));
            ((float4*)(outh + (size_t)n * 64))[s] = o;
        }
    }
}

__global__ __launch_bounds__(256)
void gather_mean_h(const __half2* __restrict__ feat, const int* __restrict__ row_ptr,
                   const int* __restrict__ csr_src, const float* __restrict__ deg_inv,
                   __half2* __restrict__ outv) {
    gather_core<false>(feat, row_ptr, csr_src, deg_inv, outv, nullptr);
}

__global__ __launch_bounds__(256)
void gather_mean_add_f32(const __half2* __restrict__ feat, const int* __restrict__ row_ptr,
                         const int* __restrict__ csr_src, const float* __restrict__ deg_inv,
                         float* __restrict__ out) {
    gather_core<true>(feat, row_ptr, csr_src, deg_inv, nullptr, out);
}

// ---------------- producer-consumer fused MFMA GEMM --------------------------
// Fused dataflow of R1 (h lives only in LDS) but wave-specialized:
//   waves 0-3 (producers): h(16x256) = relu(mean1@Wl1^T + xb@Wr1^T + b1);
//     wave w owns h cols [w*64,+64); holds only bf1 (128 VGPR of B).
//   waves 4-7 (consumers): P = h@Wl2^T ; OUT = h@Wr2^T + b2, one tile behind;
//     wave cw owns 32 cols of P and OUT; holds only bf20/21 (128 VGPR of B).
// ldsH double-buffered; ONE barrier per tile (vs 2 in R1); both MFMA phases
// active simultaneously; per-wave B state halved vs R1 -> better occupancy.
// Barrier counts identical across groups by construction.
// mfma_f32_16x16x32_f16 layouts (verified R4..R11 + rounds 1-5 numerics):
//   A frag: lane holds A[m = lane&15][k = kc*32 + (lane>>4)*8 + j]
//   B frag: lane holds W[n = lane&15][k]  (W row-major [J,K])
//   C/D:    col = lane&15 (n), row = (lane>>4)*4 + reg

#define HPAD 264

__global__ __launch_bounds__(512, 1)
void gemm_pc(const __half* __restrict__ Aa,   // mean1 fp16 [N,128]
             const __half* __restrict__ Ab,   // xb fp16 [N,128]
             const __half* __restrict__ Wl1h, const __half* __restrict__ Wr1h,
             const float* __restrict__ bias1,
             const __half* __restrict__ B20, const __half* __restrict__ B21,
             const float* __restrict__ bias2,
             __half* __restrict__ P, float* __restrict__ out) {
    __shared__ __half ldsH[2][16][HPAD];
    const int lane = threadIdx.x & 63;
    const int wave = threadIdx.x >> 6;      // 0..7
    const int quad = lane >> 4;
    const int l16 = lane & 15;
    const int koff = quad * 8;
    const int g = gridDim.x;

    if (wave < 4) {
        // ================= producer =================
        f16x8 bf1[2][4][4];
        #pragma unroll
        for (int p = 0; p < 2; ++p) {
            const __half* __restrict__ B = p ? Wr1h : Wl1h;
            #pragma unroll
            for (int kc = 0; kc < 4; ++kc)
                #pragma unroll
                for (int nt = 0; nt < 4; ++nt)
                    bf1[p][kc][nt] = *(const f16x8*)(
                        B + (size_t)(wave * 64 + nt * 16 + l16) * D_IN + kc * 32 + koff);
        }
        float bv1[4];
        #pragma unroll
        for (int nt = 0; nt < 4; ++nt) bv1[nt] = bias1[wave * 64 + nt * 16 + l16];

        auto loadA = [&](int t, f16x8 (&am)[4], f16x8 (&ax)[4]) {
            const size_t arow = (size_t)(t * 16 + l16) * D_IN + koff;
            #pragma unroll
            for (int kc = 0; kc < 4; ++kc) {
                am[kc] = *(const f16x8*)(Aa + arow + kc * 32);
                ax[kc] = *(const f16x8*)(Ab + arow + kc * 32);
            }
        };
        auto produce = [&](const f16x8 (&am)[4], const f16x8 (&ax)[4], int buf) {
            f32x4 acc1[4] = {};
            #pragma unroll
            for (int kc = 0; kc < 4; ++kc)
                #pragma unroll
                for (int nt = 0; nt < 4; ++nt) {
                    acc1[nt] = __builtin_amdgcn_mfma_f32_16x16x32_f16(
                        am[kc], bf1[0][kc][nt], acc1[nt], 0, 0, 0);
                    acc1[nt] = __builtin_amdgcn_mfma_f32_16x16x32_f16(
                        ax[kc], bf1[1][kc][nt], acc1[nt], 0, 0, 0);
                }
            #pragma unroll
            for (int nt = 0; nt < 4; ++nt) {
                int col = wave * 64 + nt * 16 + l16;
                #pragma unroll
                for (int r = 0; r < 4; ++r)
                    ldsH[buf][quad * 4 + r][col] =
                        __float2half(fmaxf(acc1[nt][r] + bv1[nt], 0.f));
            }
        };

        f16x8 am0[4], ax0[4], am1[4], ax1[4];
        int tile = blockIdx.x;
        loadA(tile, am0, ax0);
        while (true) {
            if (tile + g < NTILES) loadA(tile + g, am1, ax1);
            produce(am0, ax0, 0);
            __syncthreads();
            tile += g;
            if (tile >= NTILES) break;
            if (tile + g < NTILES) loadA(tile + g, am0, ax0);
            produce(am1, ax1, 1);
            __syncthreads();
            tile += g;
            if (tile >= NTILES) break;
        }
    } else {
        // ================= consumer =================
        const int cw = wave - 4;            // 0..3, owns 32 cols of P and OUT
        f16x8 bf20[8][2], bf21[8][2];
        #pragma unroll
        for (int kc = 0; kc < 8; ++kc)
            #pragma unroll
            for (int nt = 0; nt < 2; ++nt) {
                size_t brow = (size_t)(cw * 32 + nt * 16 + l16) * D_HID + kc * 32 + koff;
                bf20[kc][nt] = *(const f16x8*)(B20 + brow);
                bf21[kc][nt] = *(const f16x8*)(B21 + brow);
            }
        float bv2[2];
        #pragma unroll
        for (int nt = 0; nt < 2; ++nt) bv2[nt] = bias2[cw * 32 + nt * 16 + l16];

        auto consume = [&](int t, int buf) {
            f32x4 acc20[2] = {};
            f32x4 acc21[2] = {};
            #pragma unroll
            for (int kc = 0; kc < 8; ++kc) {
                f16x8 a2 = *(const f16x8*)&ldsH[buf][l16][kc * 32 + koff];
                #pragma unroll
                for (int nt = 0; nt < 2; ++nt) {
                    acc20[nt] = __builtin_amdgcn_mfma_f32_16x16x32_f16(
                        a2, bf20[kc][nt], acc20[nt], 0, 0, 0);
                    acc21[nt] = __builtin_amdgcn_mfma_f32_16x16x32_f16(
                        a2, bf21[kc][nt], acc21[nt], 0, 0, 0);
                }
            }
            #pragma unroll
            for (int nt = 0; nt < 2; ++nt) {
                int col = cw * 32 + nt * 16 + l16;
                #pragma unroll
                for (int r = 0; r < 4; ++r) {
                    int row = t * 16 + quad * 4 + r;
                    P[(size_t)row * D_OUT + col] = __float2half(acc20[nt][r]);
                    out[(size_t)row * D_OUT + col] = acc21[nt][r] + bv2[nt];
                }
            }
        };

        int tile = blockIdx.x;
        int prevTile = -1, prevBuf = 0, buf = 0;
        while (tile < NTILES) {
            if (prevTile >= 0) consume(prevTile, prevBuf);
            __syncthreads();
            prevTile = tile;
            prevBuf = buf;
            buf ^= 1;
            tile += g;
        }
        if (prevTile >= 0) consume(prevTile, prevBuf);
    }
}

extern "C" void kernel_launch(void* const* d_in, const int* in_sizes, int n_in,
                              void* d_out, int out_size, void* d_ws, size_t ws_size,
                              hipStream_t stream) {
    const float* x   = (const float*)d_in[0];
    const float* Wl1 = (const float*)d_in[1];
    const float* bl1 = (const float*)d_in[2];
    const float* Wr1 = (const float*)d_in[3];
    const float* Wl2 = (const float*)d_in[4];
    const float* bl2 = (const float*)d_in[5];
    const float* Wr2 = (const float*)d_in[6];
    const int*   ei  = (const int*)d_in[7];
    const int* src = ei;              // edge_index[0]
    const int* dst = ei + N_EDGES;    // edge_index[1]
    float* out = (float*)d_out;

    // Workspace layout, 256B-aligned slabs
    char* w = (char*)d_ws;
    auto alloc = [&](size_t bytes) {
        char* r = w;
        w += (bytes + 255) & ~(size_t)255;
        return r;
    };
    int*     deg       = (int*)alloc((size_t)N_NODES * 4);
    int*     row_ptr   = (int*)alloc((size_t)(N_NODES + 1) * 4);
    int*     rank      = (int*)alloc((size_t)N_EDGES * 4);
    int*     csr_src   = (int*)alloc((size_t)N_EDGES * 4);
    float*   deg_inv   = (float*)alloc((size_t)N_NODES * 4);
    __half2* xb        = (__half2*)alloc((size_t)N_NODES * 64 * 4);   // x fp16
    __half2* mean1     = (__half2*)alloc((size_t)N_NODES * 64 * 4);   // mean(x) fp16
    __half2* pb        = (__half2*)alloc((size_t)N_NODES * 64 * 4);   // h@Wl2^T fp16
    __half*  wl1h      = (__half*)alloc(4 * 32768 * 2);
    __half*  wr1h = wl1h + 32768;
    __half*  wl2h = wr1h + 32768;
    __half*  wr2h = wl2h + 32768;

    // deg = 0 (async memset is graph-capturable; harness uses it itself)
    hipMemsetAsync(deg, 0, (size_t)N_NODES * 4, stream);

    // Merged prep (x/weights -> fp16) + deg/rank atomics (independent work)
    prep_deg_rank<<<6266, 256, 0, stream>>>(x, (__half*)xb, Wl1, Wr1, Wl2, Wr2,
        wl1h, wr1h, wl2h, wr2h, dst, deg, rank);

    // CSR scan (chunk_sum folded in) + scatter
    scatter_scan<<<NCHUNK, 256, 0, stream>>>(deg, row_ptr, deg_inv);
    fill_csr<<<(N_EDGES + 255) / 256, 256, 0, stream>>>(src, dst, rank, row_ptr, csr_src);

    // Layer 1 aggregation (full TLP: 12500 blocks, wave per node)
    gather_mean_h<<<12500, 256, 0, stream>>>(xb, row_ptr, csr_src, deg_inv, mean1);

    // Producer-consumer fused GEMMs: h in LDS; P = h@Wl2^T; out = h@Wr2^T + b2
    gemm_pc<<<GEMM_GRID, 512, 0, stream>>>(
        (const __half*)mean1, (const __half*)xb, wl1h, wr1h, bl1,
        wl2h, wr2h, bl2, (__half*)pb, out);

    // out += mean(P)
    gather_mean_add_f32<<<12500, 256, 0, stream>>>(pb, row_ptr, csr_src, deg_inv, out);
}